// Round 1
// baseline (50.175 us; speedup 1.0000x reference)
//
#include <hip/hip_runtime.h>

#define T_LEN 4096
#define H 16
#define N 16
#define D 64

// ---------------------------------------------------------------------------
// Phase 1: per (chunk, head) one wave (64 threads). Lane d owns the full
// n-column of the state (16 regs). Computes the chunk-local scan with zero
// initial state (L) and the chunk decay product (P).
// L layout: [c][h][n][d], P layout: [c][h]
// ---------------------------------------------------------------------------
__global__ __launch_bounds__(64)
void phase1(const float* __restrict__ x, const float* __restrict__ dt,
            const float* __restrict__ B, const float* __restrict__ mask,
            const float* __restrict__ log_decay,
            float* __restrict__ Lbuf, float* __restrict__ Pbuf, int CL) {
    const int c = blockIdx.x, h = blockIdx.y;
    const int d = threadIdx.x;
    const float rate = -__expf(log_decay[h]);

    float s[N];
#pragma unroll
    for (int n = 0; n < N; ++n) s[n] = 0.f;
    float P = 1.f;

    const int t0 = c * CL;
#pragma unroll 4
    for (int ss = 0; ss < CL; ++ss) {
        const int t = t0 + ss;
        const float dtv  = dt[t * H + h];          // wave-uniform -> s_load
        const float mv   = mask[t];                // wave-uniform
        const float Atil = (1.f - mv) * __expf(dtv * rate);
        const float xv   = x[(t * H + h) * D + d]; // per-lane, coalesced
        const float cxd  = dtv * xv;
        const float* Bp  = B + (t * H + h) * N;    // wave-uniform -> s_load
        P *= Atil;
#pragma unroll
        for (int n = 0; n < N; ++n) {
            s[n] = Atil * s[n] + Bp[n] * cxd;
        }
    }

    float* Lp = Lbuf + ((c * H + h) * N) * D + d;
#pragma unroll
    for (int n = 0; n < N; ++n) Lp[n * D] = s[n];
    if (d == 0) Pbuf[c * H + h] = P;
}

// ---------------------------------------------------------------------------
// Phase 2: 16384 threads, one per (h,n,d). Sequentially combine chunks:
//   entry_c = carry;  carry = P_c * carry + L_c
// Overwrites L in place with the chunk ENTRY states. Writes next_carry.
// 8-deep prefetch to hide load latency on the serial chain.
// ---------------------------------------------------------------------------
__global__ __launch_bounds__(256)
void phase2(const float* __restrict__ initial_carry,
            float* __restrict__ LE, const float* __restrict__ Pbuf,
            float* __restrict__ next_carry, int NC) {
    const int idx = blockIdx.x * 256 + threadIdx.x;   // h*N*D + n*D + d
    const int h = idx >> 10;                          // N*D = 1024
    float carry = initial_carry[idx];

    for (int cg = 0; cg < NC; cg += 8) {
        float l[8], p[8];
#pragma unroll
        for (int k = 0; k < 8; ++k) {
            l[k] = LE[(cg + k) * (H * N * D) + idx];
            p[k] = Pbuf[(cg + k) * H + h];
        }
#pragma unroll
        for (int k = 0; k < 8; ++k) {
            LE[(cg + k) * (H * N * D) + idx] = carry; // entry state for chunk
            carry = p[k] * carry + l[k];
        }
    }
    next_carry[idx] = carry;
}

// ---------------------------------------------------------------------------
// Phase 3: re-scan each chunk from its entry state; fuse the C-projection
// (thread-local over n) and the skip connection. One coalesced store/step.
// ---------------------------------------------------------------------------
__global__ __launch_bounds__(64)
void phase3(const float* __restrict__ x, const float* __restrict__ dt,
            const float* __restrict__ B, const float* __restrict__ C,
            const float* __restrict__ mask, const float* __restrict__ log_decay,
            const float* __restrict__ skip_weight,
            const float* __restrict__ Ebuf, float* __restrict__ out, int CL) {
    const int c = blockIdx.x, h = blockIdx.y;
    const int d = threadIdx.x;
    const float rate = -__expf(log_decay[h]);

    float s[N];
    const float* Ep = Ebuf + ((c * H + h) * N) * D + d;
#pragma unroll
    for (int n = 0; n < N; ++n) s[n] = Ep[n * D];

    const float sw = skip_weight[h * D + d];
    const int t0 = c * CL;
#pragma unroll 4
    for (int ss = 0; ss < CL; ++ss) {
        const int t = t0 + ss;
        const float dtv  = dt[t * H + h];
        const float mv   = mask[t];
        const float Atil = (1.f - mv) * __expf(dtv * rate);
        const float xv   = x[(t * H + h) * D + d];
        const float cxd  = dtv * xv;
        const float* Bp  = B + (t * H + h) * N;
        const float* Cp  = C + (t * H + h) * N;
        float acc = sw * xv;
#pragma unroll
        for (int n = 0; n < N; ++n) {
            s[n] = Atil * s[n] + Bp[n] * cxd;
            acc += Cp[n] * s[n];
        }
        out[(t * H + h) * D + d] = acc;
    }
}

extern "C" void kernel_launch(void* const* d_in, const int* in_sizes, int n_in,
                              void* d_out, int out_size, void* d_ws, size_t ws_size,
                              hipStream_t stream) {
    const float* x    = (const float*)d_in[0];
    const float* dt   = (const float*)d_in[1];
    const float* B    = (const float*)d_in[2];
    const float* C    = (const float*)d_in[3];
    const float* mask = (const float*)d_in[4];
    const float* ic   = (const float*)d_in[5];
    const float* ld   = (const float*)d_in[6];
    const float* sw   = (const float*)d_in[7];
    float* out = (float*)d_out;

    // Pick chunk count by available scratch: need NC*(H*N*D + H)*4 bytes.
    int NC = 128;
    while (NC > 16 && (size_t)NC * (H * N * D + H) * sizeof(float) > ws_size) NC >>= 1;
    const int CL = T_LEN / NC;

    float* Lbuf = (float*)d_ws;            // NC * H*N*D
    float* Pbuf = Lbuf + (size_t)NC * H * N * D;  // NC * H

    dim3 grid(NC, H), block(64);
    phase1<<<grid, block, 0, stream>>>(x, dt, B, mask, ld, Lbuf, Pbuf, CL);
    phase2<<<dim3(H * N * D / 256), dim3(256), 0, stream>>>(ic, Lbuf, Pbuf, out, NC);
    phase3<<<grid, block, 0, stream>>>(x, dt, B, C, mask, ld, sw, Lbuf, out + H * N * D, CL);
}